// Round 5
// baseline (4772.189 us; speedup 1.0000x reference)
//
#include <hip/hip_runtime.h>
#include <stdint.h>

// 2-layer masked GRU encoder, B=64 T=512 D=U=512. f32 in/out, mask=int32.
// 256 WGs, software-pipelined: even WGs (pipe A) = layer 0 at phase s, odd WGs
// (pipe B) = layer 1 at phase s-1. Cross-WG handoff via TAGGED 8B words
// {u32 tag = phase+1, 2xbf16 payload} in MALL-coherent relaxed agent atomics:
// consumers poll their exact staging words (no fence, no drain, no flag on the
// data path). WAR safety: depth-4 slot rotation + per-WG monotonic progress
// flag (set after staging reads; producers require consumer flags >= s-2
// before overwriting slot s&3, checked by wave 3 off the critical path).
// ws: h0pub[4][64][256]u64 | h1pub[4][...] | h0n[4][...] | flags[256]u32
//     == 1,573,888 bytes.

#define TT 512

typedef __attribute__((ext_vector_type(8))) short bfrag_t;   // 8 x bf16
typedef __attribute__((ext_vector_type(4))) float f32x4;
typedef unsigned long long u64;

__device__ inline unsigned short f2bf(float f) {
  unsigned u = __float_as_uint(f);
  unsigned r = u + 0x7FFFu + ((u >> 16) & 1u);   // RNE
  return (unsigned short)(r >> 16);
}
__device__ inline unsigned pack2(float lo, float hi) {
  return (unsigned)f2bf(lo) | ((unsigned)f2bf(hi) << 16);
}
__device__ inline float sigmoidf_(float x) { return 1.0f / (1.0f + __expf(-x)); }
__device__ inline float fast_tanh(float x) {
  float ax = fabsf(x);
  float e = __expf(-2.0f * ax);
  float t = (1.0f - e) / (1.0f + e);
  return x < 0.0f ? -t : t;
}

__device__ inline void st8(u64* p, u64 v) {
  __hip_atomic_store(p, v, __ATOMIC_RELAXED, __HIP_MEMORY_SCOPE_AGENT);
}
__device__ inline u64 ld8(const u64* p) {
  return __hip_atomic_load(p, __ATOMIC_RELAXED, __HIP_MEMORY_SCOPE_AGENT);
}
__device__ inline unsigned ld4(const unsigned* p) {
  return __hip_atomic_load(p, __ATOMIC_RELAXED, __HIP_MEMORY_SCOPE_AGENT);
}

// Poll 16 tagged words until all carry `tag`; payloads -> dst32[0..15].
__device__ inline void poll16(const u64* src, unsigned tag, unsigned* dst32) {
  u64 v[16];
  for (;;) {
    bool ok = true;
    #pragma unroll
    for (int j = 0; j < 16; ++j) v[j] = ld8(src + j);
    #pragma unroll
    for (int j = 0; j < 16; ++j) ok &= ((unsigned)(v[j] >> 32) == tag);
    if (ok) break;
  }
  #pragma unroll
  for (int j = 0; j < 16; ++j) dst32[j] = (unsigned)v[j];
}

extern "C" __global__ void __launch_bounds__(256, 1)
gru2_tagged(const float* __restrict__ x,     // [64][512][512] f32
            const int*   __restrict__ mask,  // [64][512] i32
            const float* __restrict__ W0,    // [512][1536] f32
            const float* __restrict__ U0,
            const float* __restrict__ b0,    // [2][1536]
            const float* __restrict__ W1,
            const float* __restrict__ U1,
            const float* __restrict__ b1,
            float* __restrict__ out,         // [16777216 + 2*32768] f32
            unsigned char* __restrict__ ws)
{
  extern __shared__ unsigned short sm[];
  unsigned short* wt  = sm;                 // [96][520] bf16 transposed weights
  unsigned short* st0 = sm + 96 * 520;      // [16][520] input operand (x or h0n)
  unsigned short* st1 = st0 + 16 * 520;     // [16][520] hidden operand
  float* accs = (float*)(st1 + 16 * 520);   // [4][256]
  unsigned short* pub16 = (unsigned short*)(accs + 1024);  // [2][16][16]

  u64* h0pub = (u64*)ws;                    // [4][64][256] tagged words
  u64* h1pub = (u64*)(ws + 524288);
  u64* h0n   = (u64*)(ws + 1048576);
  unsigned* flags = (unsigned*)(ws + 1572864);  // [256] monotonic progress

  const int tid  = threadIdx.x;
  const int wg   = blockIdx.x;
  const int pipe = wg & 1;
  const int idx  = wg >> 1;
  const int mi = idx & 3,  ni = idx >> 2;     // 4 row-groups x 32 col-groups
  const int r0 = mi * 16,  c0 = ni * 16;
  const int wave = tid >> 6, lane = tid & 63;
  const int quad = lane >> 4, n16 = lane & 15;

  const float* Wm = pipe ? W1 : W0;
  const float* Um = pipe ? U1 : U0;
  const float* bp = pipe ? b1 : b0;
  u64* hpub = pipe ? h1pub : h0pub;

  // ---- one-time: transpose my 48 gate-cols of W and U into LDS bf16 [n][k] ----
  {
    const int col  = tid & 15;
    const int ksub = tid >> 4;
    for (int k0 = 0; k0 < 512; k0 += 16) {
      const int k = k0 + ksub;
      const float* M0 = Wm + (size_t)k * 1536;
      const float* M1 = Um + (size_t)k * 1536;
      #pragma unroll
      for (int g = 0; g < 3; ++g) {
        wt[(g * 16 + col) * 520 + k]      = f2bf(M0[g * 512 + c0 + col]);
        wt[(48 + g * 16 + col) * 520 + k] = f2bf(M1[g * 512 + c0 + col]);
      }
    }
  }
  __syncthreads();

  // wave roles: w0=z (concat x|h), w1=r (concat), w2=ih (x), w3=hh (h)
  const int g  = (wave < 2) ? wave : 2;
  const int np = (wave < 2) ? 2 : 1;

  bfrag_t bw0[16], bw1[16];
  {
    const int mat0 = (wave == 3) ? 1 : 0;
    const int row0 = mat0 * 48 + g * 16 + n16;
    #pragma unroll
    for (int f = 0; f < 16; ++f)
      bw0[f] = *(const bfrag_t*)&wt[row0 * 520 + f * 32 + quad * 8];
    if (np == 2) {
      const int row1 = 48 + g * 16 + n16;
      #pragma unroll
      for (int f = 0; f < 16; ++f)
        bw1[f] = *(const bfrag_t*)&wt[row1 * 520 + f * 32 + quad * 8];
    }
  }

  float bsc;
  {
    const int colg = g * 512 + c0 + n16;
    const float bi = bp[colg];
    const float bh = bp[1536 + colg];
    bsc = (wave < 2) ? (bi + bh) : ((wave == 2) ? bi : bh);
  }

  // WAR-flag pointer for wave 3 lanes: pipe A watches both pipes of its
  // mi-group (64 consumers), pipe B watches pipe-B mi-group (32).
  const unsigned* flp = nullptr;
  if (wave == 3) {
    if (pipe == 0) flp = flags + ((lane < 32) ? (mi * 32 + lane)
                                              : (128 + mi * 32 + (lane - 32)));
    else if (lane < 32) flp = flags + (128 + mi * 32 + lane);
  }

  float hcar = 0.0f;   // fp32 carry of my h element (WG-local)
  float oprev = 0.0f;
  const int erow = tid >> 4, ecol = tid & 15;
  const int eb = r0 + erow, ec = c0 + ecol;

  const int row = tid >> 4;          // staging: my row 0..15
  const int seg = tid & 15;          // my 32-col segment
  unsigned* st0u = (unsigned*)st0;
  unsigned* st1u = (unsigned*)st1;
  const int sbase = row * 260 + seg * 16;  // u32 index into st (520 u16 stride)

  for (int s = 0; s <= TT; ++s) {
    const bool actA = (pipe == 0) && (s < TT);
    const bool actB = (pipe == 1) && (s > 0);
    const bool act  = actA || actB;
    const int  t    = pipe ? (s - 1) : s;

    const int mv = act ? mask[(size_t)eb * 512 + t] : 0;

    // early-issue WAR flag sample (checked after MFMA)
    int flagv = 0x7FFFFFFF;
    if (act && flp) flagv = (int)ld4(flp);

    // ---- staging: poll tagged words, write LDS ----
    if (act) {
      const size_t rslot = (size_t)((s + 3) & 3) * 16384;   // consumer slot
      const size_t woff  = (size_t)(r0 + row) * 256 + seg * 16;
      if (actA) {
        // issue x loads first (overlap with polling)
        const float* src = x + ((size_t)(r0 + row) * 512 + s) * 512 + seg * 32;
        float4 xf[8];
        #pragma unroll
        for (int j = 0; j < 8; ++j) xf[j] = ((const float4*)src)[j];
        unsigned hv[16];
        poll16(hpub + rslot + woff, (unsigned)s, hv);
        #pragma unroll
        for (int j = 0; j < 16; ++j) st1u[sbase + j] = hv[j];
        #pragma unroll
        for (int j = 0; j < 8; ++j) {
          st0u[sbase + 2 * j]     = pack2(xf[j].x, xf[j].y);
          st0u[sbase + 2 * j + 1] = pack2(xf[j].z, xf[j].w);
        }
      } else {
        unsigned nv[16];
        poll16(h0n + rslot + woff, (unsigned)s, nv);   // h0n(t), tag s
        #pragma unroll
        for (int j = 0; j < 16; ++j) st0u[sbase + j] = nv[j];
        if (s == 1) {                                   // h1(-1) = 0
          #pragma unroll
          for (int j = 0; j < 16; ++j) st1u[sbase + j] = 0u;
        } else {
          unsigned hv[16];
          poll16(h1pub + rslot + woff, (unsigned)s, hv);
          #pragma unroll
          for (int j = 0; j < 16; ++j) st1u[sbase + j] = hv[j];
        }
      }
    }
    __syncthreads();
    // progress flag: this WG finished its phase-s reads
    if (tid == 0)
      __hip_atomic_store(&flags[pipe * 128 + mi * 32 + ni], (unsigned)(s + 1),
                         __ATOMIC_RELAXED, __HIP_MEMORY_SCOPE_AGENT);

    // ---- MFMA ----
    if (act) {
      f32x4 acc = {bsc, bsc, bsc, bsc};
      const unsigned short* s0 = (wave == 3) ? st1 : st0;
      const int abase = n16 * 520 + quad * 8;
      #pragma unroll
      for (int f = 0; f < 16; ++f) {
        bfrag_t a = *(const bfrag_t*)&s0[abase + f * 32];
        acc = __builtin_amdgcn_mfma_f32_16x16x32_bf16(a, bw0[f], acc, 0, 0, 0);
      }
      if (np == 2) {
        #pragma unroll
        for (int f = 0; f < 16; ++f) {
          bfrag_t a = *(const bfrag_t*)&st1[abase + f * 32];
          acc = __builtin_amdgcn_mfma_f32_16x16x32_bf16(a, bw1[f], acc, 0, 0, 0);
        }
      }
      #pragma unroll
      for (int i = 0; i < 4; ++i)
        accs[wave * 256 + (quad * 4 + i) * 16 + n16] = acc[i];  // row=quad*4+i, col=n16

      // WAR check: consumers of my slot (s&3) must be past phase s-3
      if (flp) {
        int need = s - 2;
        int fv = flagv;
        while (fv < need) fv = (int)ld4(flp);
      }
    }
    __syncthreads();

    // ---- elementwise GRU cell (register h-carry) ----
    if (act) {
      const float zv = sigmoidf_(accs[tid]);
      const float rv = sigmoidf_(accs[256 + tid]);
      const float candv = fast_tanh(accs[512 + tid] + rv * accs[768 + tid]);
      const float hold = hcar;
      const float hn = zv * hold + (1.0f - zv) * candv;
      const bool  m  = mv != 0;
      const float hc = m ? hn : hold;
      hcar = hc;
      pub16[erow * 16 + ecol] = f2bf(hc);
      if (pipe == 0) {
        pub16[256 + erow * 16 + ecol] = f2bf(hn);   // UNMASKED h0n for layer 1
        if (t == TT - 1) out[(size_t)16777216 + (size_t)eb * 512 + ec] = hc;         // h0f
      } else {
        const float ov = m ? hn : oprev;
        oprev = ov;
        out[(size_t)eb * 262144 + (size_t)t * 512 + ec] = ov;                         // output
        if (t == TT - 1) out[(size_t)16777216 + 32768 + (size_t)eb * 512 + ec] = hc;  // h1f
      }
    }
    __syncthreads();

    // ---- tagged publish (no drain, no flag) ----
    if (act) {
      const int npub = (pipe == 0) ? 256 : 128;
      if (tid < npub) {
        const int str = tid >> 7;            // 0: masked h, 1: h0n (pipe A)
        const int r   = (tid >> 3) & 15;
        const int w   = tid & 7;
        const unsigned lo = *(const unsigned*)&pub16[str * 256 + r * 16 + 2 * w];
        const u64 val = ((u64)(unsigned)(s + 1) << 32) | lo;
        u64* base = (pipe == 0) ? (str ? h0n : h0pub) : h1pub;
        st8(base + (size_t)(s & 3) * 16384 + (size_t)(r0 + r) * 256 + c0 / 2 + w, val);
      }
    }
  }
}

extern "C" void kernel_launch(void* const* d_in, const int* in_sizes, int n_in,
                              void* d_out, int out_size, void* d_ws, size_t ws_size,
                              hipStream_t stream) {
  (void)in_sizes; (void)n_in; (void)out_size;
  const float* x    = (const float*)d_in[0];
  const int*   mask = (const int*)  d_in[1];
  const float* W0   = (const float*)d_in[2];
  const float* U0   = (const float*)d_in[3];
  const float* b0   = (const float*)d_in[4];
  const float* W1   = (const float*)d_in[5];
  const float* U1   = (const float*)d_in[6];
  const float* b1   = (const float*)d_in[7];
  float* out = (float*)d_out;
  unsigned char* ws = (unsigned char*)d_ws;

  const size_t need = 1573888;   // 3 x 4-slot tagged buffers + flags
  const size_t zb = ws_size < need ? ws_size : need;
  hipMemsetAsync(d_ws, 0, zb, stream);

  hipFuncSetAttribute((const void*)gru2_tagged,
                      hipFuncAttributeMaxDynamicSharedMemorySize, 138240);
  void* args[] = { (void*)&x, (void*)&mask, (void*)&W0, (void*)&U0, (void*)&b0,
                   (void*)&W1, (void*)&U1, (void*)&b1, (void*)&out, (void*)&ws };
  hipLaunchCooperativeKernel((void*)gru2_tagged, dim3(256), dim3(256),
                             args, 138240, stream);
}